// Round 6
// baseline (240.857 us; speedup 1.0000x reference)
//
#include <hip/hip_runtime.h>
#include <hip/hip_fp16.h>

#define DM 128
#define NHEADS 8
#define MAXDEG 64
#define SROW 136   // LDS row stride in halves: 128+8 pad (2-way bank alias = free)

typedef _Float16 half8 __attribute__((ext_vector_type(8)));
typedef _Float16 half2v __attribute__((ext_vector_type(2)));
typedef float floatx4 __attribute__((ext_vector_type(4)));

union H16 { half8 v8[2]; half2v h2[8]; _Float16 h[16]; };

// ================= fused: proj GEMM blocks [0,P) + CSR-build blocks [P,P+C) =================
// proj: X(Mx128,f32) @ Wcat^T(576x128) with inline f32->f16 W conversion during staging.
// one proj block = 128 M-rows x all 576 N-cols (9 chunks of 64). X read exactly once.
// chunk pairs: 0,1->Q  2,3->K(KV lo)  4,5->V(KV hi)  6,7->sigmoid gate  8->bias cols 512..519
// CSR blocks: 1 edge/thread (shortest dependent chain: load -> atomic -> scatter store);
// their latency overlaps the co-resident proj blocks' MFMA/staging.
__global__ __launch_bounds__(256) void proj_csr(
    const float* __restrict__ X, const float* __restrict__ Wqkv,
    const float* __restrict__ Wgate, const float* __restrict__ wbias,
    const float* __restrict__ b_gate,
    const int* __restrict__ nsrc, const int* __restrict__ ndst,
    int* __restrict__ cnt, int* __restrict__ csr_dst,
    _Float16* __restrict__ Q, _Float16* __restrict__ KV,
    _Float16* __restrict__ gate, float* __restrict__ bias,
    int M, int E, int P) {
  __shared__ _Float16 As[128 * SROW];
  __shared__ _Float16 Bs[64 * SROW];
  int tid = threadIdx.x;
  int bid = blockIdx.x;

  if (bid >= P) {
    // ---------------- CSR build role: 1 edge per thread ----------------
    int e = (bid - P) * 256 + tid;
    if (e < E) {
      int s = nsrc[e];
      int d = ndst[e];
      int p = atomicAdd(&cnt[s], 1);
      if (p < MAXDEG) csr_dst[(size_t)s * MAXDEG + p] = d;
    }
    return;
  }

  // ---------------- projection GEMM role ----------------
  int m0 = bid * 128;

  // stage A (fp32 -> fp16): 128 rows x 128 cols
#pragma unroll
  for (int i = 0; i < 4; i++) {
    int u = tid + i * 256;           // 0..1023
    int r = u >> 3;
    int cc = (u & 7) * 16;
    int gr = m0 + r;
    float4 f0, f1, f2, f3;
    if (gr < M) {
      const float4* src = (const float4*)(X + (size_t)gr * 128 + cc);
      f0 = src[0]; f1 = src[1]; f2 = src[2]; f3 = src[3];
    } else {
      f0 = f1 = f2 = f3 = make_float4(0.f, 0.f, 0.f, 0.f);
    }
    half8 h0 = {(_Float16)f0.x, (_Float16)f0.y, (_Float16)f0.z, (_Float16)f0.w,
                (_Float16)f1.x, (_Float16)f1.y, (_Float16)f1.z, (_Float16)f1.w};
    half8 h1 = {(_Float16)f2.x, (_Float16)f2.y, (_Float16)f2.z, (_Float16)f2.w,
                (_Float16)f3.x, (_Float16)f3.y, (_Float16)f3.z, (_Float16)f3.w};
    *(half8*)(As + r * SROW + cc) = h0;
    *(half8*)(As + r * SROW + cc + 8) = h1;
  }

  int wid = tid >> 6, lane = tid & 63;
  int quad = lane >> 4, l16 = lane & 15;
  int mw = wid * 32;                 // wave owns 32 M-rows

  for (int c = 0; c < 9; c++) {
    __syncthreads();                 // previous chunk's Bs readers done (orders A on c=0)
    // stage B chunk c with inline f32->f16 conversion
#pragma unroll
    for (int i = 0; i < 4; i++) {
      int u = tid + i * 256;         // 0..1023
      int r = u >> 4;                // 0..63
      int cc = (u & 15) * 8;
      int grow = c * 64 + r;
      const float* src = nullptr;
      if (grow < 384)      src = Wqkv + (size_t)grow * 128 + cc;
      else if (grow < 512) src = Wgate + (size_t)(grow - 384) * 128 + cc;
      else if (grow < 520) src = wbias + (size_t)(grow - 512) * 128 + cc;
      half8 h = {};
      if (src) {
        float4 f0 = ((const float4*)src)[0];
        float4 f1 = ((const float4*)src)[1];
        h = half8{(_Float16)f0.x, (_Float16)f0.y, (_Float16)f0.z, (_Float16)f0.w,
                  (_Float16)f1.x, (_Float16)f1.y, (_Float16)f1.z, (_Float16)f1.w};
      }
      *(half8*)(Bs + r * SROW + cc) = h;
    }
    __syncthreads();

    floatx4 acc[2][4] = {};
#pragma unroll
    for (int kc = 0; kc < 4; kc++) {
      int ko = kc * 32 + quad * 8;
      half8 a0 = *(const half8*)(As + (mw + l16) * SROW + ko);
      half8 a1 = *(const half8*)(As + (mw + 16 + l16) * SROW + ko);
      half8 b[4];
#pragma unroll
      for (int ni = 0; ni < 4; ni++)
        b[ni] = *(const half8*)(Bs + (ni * 16 + l16) * SROW + ko);
#pragma unroll
      for (int ni = 0; ni < 4; ni++) {
        acc[0][ni] = __builtin_amdgcn_mfma_f32_16x16x32_f16(a0, b[ni], acc[0][ni], 0, 0, 0);
        acc[1][ni] = __builtin_amdgcn_mfma_f32_16x16x32_f16(a1, b[ni], acc[1][ni], 0, 0, 0);
      }
    }

    if (c == 8) {                    // bias chunk: only cols 512..519 real
      if (l16 < 8) {
#pragma unroll
        for (int mi = 0; mi < 2; mi++)
#pragma unroll
          for (int r = 0; r < 4; r++) {
            int row = m0 + mw + mi * 16 + quad * 4 + r;
            if (row < M) bias[(size_t)row * 8 + l16] = acc[mi][0][r];
          }
      }
    } else {
      int reg = c >> 1;              // 0:Q 1:K 2:V 3:gate (wave-uniform)
#pragma unroll
      for (int mi = 0; mi < 2; mi++) {
#pragma unroll
        for (int ni = 0; ni < 4; ni++) {
          int colL = (c & 1) * 64 + ni * 16 + l16;   // 0..127 within region
#pragma unroll
          for (int r = 0; r < 4; r++) {
            int row = m0 + mw + mi * 16 + quad * 4 + r;
            if (row >= M) continue;
            float v = acc[mi][ni][r];
            if (reg == 0)      Q[(size_t)row * 128 + colL] = (_Float16)v;
            else if (reg == 1) KV[(size_t)row * 256 + colL] = (_Float16)v;
            else if (reg == 2) KV[(size_t)row * 256 + 128 + colL] = (_Float16)v;
            else gate[(size_t)row * 128 + colL] =
                   (_Float16)(1.0f / (1.0f + __expf(-(v + b_gate[colL]))));
          }
        }
      }
    }
  }
}

// ======== fused attention + output GEMM: 1024 threads = 16 waves = 16 nodes/block ========
// attn: eighth-wave per edge. lane = g*8 + h (g=edge slot 0..7, h=head 0..7);
// lane owns the FULL head slice [h*16, h*16+16): score dot is in-lane (8 fdot2, no shfl),
// V-accumulate in-lane; combine the 8 edge-slot partials by butterfly over g.
// epilogue: gated 16x128 fp16 tile -> LDS; waves 0..7 do 16x128 @ Wo^T via MFMA -> out f32.
__global__ __launch_bounds__(1024) void attn_out(
    const int* __restrict__ cnt, const int* __restrict__ csr_dst,
    const _Float16* __restrict__ Q, const _Float16* __restrict__ KV,
    const float* __restrict__ bias, const _Float16* __restrict__ gate,
    const float* __restrict__ Wo, float* __restrict__ out, int N) {
  __shared__ _Float16 Ws[128 * SROW];   // Wo in fp16, row-major [ocol][k]
  __shared__ _Float16 Gs[16 * SROW];    // gated tile [node-slot][ch]
  int tid = threadIdx.x;

  // stage Wo fp32 -> fp16 (all 1024 threads, 2 half8 units each)
#pragma unroll
  for (int i = 0; i < 2; i++) {
    int u = tid + i * 1024;          // 0..2047
    int r = u >> 4;                  // 0..127
    int cc = (u & 15) * 8;
    const float4* s = (const float4*)(Wo + (size_t)r * 128 + cc);
    float4 f0 = s[0], f1 = s[1];
    half8 h = {(_Float16)f0.x, (_Float16)f0.y, (_Float16)f0.z, (_Float16)f0.w,
               (_Float16)f1.x, (_Float16)f1.y, (_Float16)f1.z, (_Float16)f1.w};
    *(half8*)(Ws + r * SROW + cc) = h;
  }

  int wid = tid >> 6, lane = tid & 63;
  int n0 = blockIdx.x * 16;
  int n = n0 + wid;
  bool active = n < N;
  int n_eff = active ? n : 0;
  int g = lane >> 3, h = lane & 7;
  int ch0 = h * 16;

  int deg = active ? cnt[n_eff] : 0;
  if (deg > MAXDEG) deg = MAXDEG;
  int dstv = csr_dst[(size_t)n_eff * MAXDEG + lane];

  H16 qu;
  qu.v8[0] = *(const half8*)(Q + (size_t)n_eff * DM + ch0);
  qu.v8[1] = *(const half8*)(Q + (size_t)n_eff * DM + ch0 + 8);
  float bias_h = bias[(size_t)n_eff * NHEADS + h];

  float acc[16] = {};
  float den = 0.f;
  int iters = (deg + 7) >> 3;        // 8 edges per iteration (one per eighth-wave)

  H16 k0, v0, k1, v1;
  k0.v8[0] = half8{}; k0.v8[1] = half8{};
  v0.v8[0] = half8{}; v0.v8[1] = half8{};
  k1 = k0; v1 = v0;
  bool b0 = false, b1 = false;
  if (0 < iters) {
    int e = g;
    b0 = e < deg;
    int d = __shfl(dstv, e);
    d = b0 ? d : 0;
    const _Float16* kvp = KV + (size_t)d * 256 + ch0;
    k0.v8[0] = *(const half8*)kvp;       k0.v8[1] = *(const half8*)(kvp + 8);
    v0.v8[0] = *(const half8*)(kvp + 128); v0.v8[1] = *(const half8*)(kvp + 136);
  }
  if (1 < iters) {
    int e = 8 + g;
    b1 = e < deg;
    int d = __shfl(dstv, e);
    d = b1 ? d : 0;
    const _Float16* kvp = KV + (size_t)d * 256 + ch0;
    k1.v8[0] = *(const half8*)kvp;       k1.v8[1] = *(const half8*)(kvp + 8);
    v1.v8[0] = *(const half8*)(kvp + 128); v1.v8[1] = *(const half8*)(kvp + 136);
  }

  for (int it = 0; it < iters; it++) {
    H16 k2, v2;
    k2.v8[0] = half8{}; k2.v8[1] = half8{};
    v2.v8[0] = half8{}; v2.v8[1] = half8{};
    bool b2 = false;
    if (it + 2 < iters) {            // wave-uniform branch
      int e = (it + 2) * 8 + g;      // <= 63 since deg <= 64
      b2 = e < deg;
      int d = __shfl(dstv, e);
      d = b2 ? d : 0;
      const _Float16* kvp = KV + (size_t)d * 256 + ch0;
      k2.v8[0] = *(const half8*)kvp;       k2.v8[1] = *(const half8*)(kvp + 8);
      v2.v8[0] = *(const half8*)(kvp + 128); v2.v8[1] = *(const half8*)(kvp + 136);
    }
    // in-lane head dot over 16 channels (no cross-lane reduce needed)
    float p = 0.f;
#pragma unroll
    for (int j = 0; j < 8; j++)
      p = __builtin_amdgcn_fdot2(qu.h2[j], k0.h2[j], p, false);
    float w = __expf(p * 0.25f + bias_h);  // scale=1/sqrt(16); scores O(10), fp32-safe
    if (!b0) w = 0.f;
    den += w;
#pragma unroll
    for (int j = 0; j < 16; j++) acc[j] = fmaf(w, (float)v0.h[j], acc[j]);
    k0 = k1; v0 = v1; b0 = b1;
    k1 = k2; v1 = v2; b1 = b2;
  }
  // combine the 8 edge-slot partials (butterfly over g: masks 8,16,32)
#pragma unroll
  for (int j = 0; j < 16; j++) {
    acc[j] += __shfl_xor(acc[j], 8);
    acc[j] += __shfl_xor(acc[j], 16);
    acc[j] += __shfl_xor(acc[j], 32);
  }
  den += __shfl_xor(den, 8);
  den += __shfl_xor(den, 16);
  den += __shfl_xor(den, 32);

  if (g == 0) {                      // lanes 0..7: head h's 16 channels
    float inv = 1.0f / (den + 1e-12f);
    H16 gv;
    gv.v8[0] = *(const half8*)(gate + (size_t)n_eff * DM + ch0);
    gv.v8[1] = *(const half8*)(gate + (size_t)n_eff * DM + ch0 + 8);
    H16 o;
#pragma unroll
    for (int j = 0; j < 16; j++)
      o.h[j] = active ? (_Float16)(acc[j] * inv * (float)gv.h[j]) : (_Float16)0.f;
    *(half8*)(Gs + wid * SROW + ch0) = o.v8[0];
    *(half8*)(Gs + wid * SROW + ch0 + 8) = o.v8[1];
  }

  __syncthreads();

  // output GEMM: out(16x128) = Gs(16x128) @ Ws^T; wave w (<8) covers cols [w*16, w*16+16)
  if (wid < 8) {
    int quad = lane >> 4, l16 = lane & 15;
    floatx4 oc = {};
#pragma unroll
    for (int kc = 0; kc < 4; kc++) {
      int ko = kc * 32 + quad * 8;
      half8 a = *(const half8*)(Gs + l16 * SROW + ko);
      half8 b = *(const half8*)(Ws + (wid * 16 + l16) * SROW + ko);
      oc = __builtin_amdgcn_mfma_f32_16x16x32_f16(a, b, oc, 0, 0, 0);
    }
    int col = wid * 16 + l16;
#pragma unroll
    for (int r = 0; r < 4; r++) {
      int row = n0 + quad * 4 + r;
      if (row < N) out[(size_t)row * 128 + col] = oc[r];
    }
  }
}

extern "C" void kernel_launch(void* const* d_in, const int* in_sizes, int n_in,
                              void* d_out, int out_size, void* d_ws, size_t ws_size,
                              hipStream_t stream) {
  const float* X     = (const float*)d_in[0];
  const float* Wqkv  = (const float*)d_in[1];
  const float* wbias = (const float*)d_in[2];
  const float* Wgate = (const float*)d_in[3];
  const float* bgate = (const float*)d_in[4];
  const float* Wo    = (const float*)d_in[5];
  const int*   nsrc  = (const int*)d_in[6];
  const int*   ndst  = (const int*)d_in[7];
  int N = in_sizes[0] / 128;
  int E = in_sizes[6];
  float* out = (float*)d_out;

  char* p = (char*)d_ws;
  _Float16* Q16     = (_Float16*)p; p += (size_t)N * 128 * sizeof(_Float16);
  _Float16* KV16    = (_Float16*)p; p += (size_t)N * 256 * sizeof(_Float16);
  _Float16* gate16  = (_Float16*)p; p += (size_t)N * 128 * sizeof(_Float16);
  float* bias       = (float*)p;    p += (size_t)N * 8 * sizeof(float);
  int* cnt          = (int*)p;      p += (size_t)N * sizeof(int);
  int* csr_dst      = (int*)p;      p += (size_t)N * MAXDEG * sizeof(int);

  hipMemsetAsync(cnt, 0, (size_t)N * sizeof(int), stream);

  int P = (N + 127) / 128;                 // proj blocks
  int C = (E + 255) / 256;                 // csr blocks, 1 edge/thread
  proj_csr<<<P + C, 256, 0, stream>>>(X, Wqkv, Wgate, wbias, bgate, nsrc, ndst,
                                      cnt, csr_dst, Q16, KV16, gate16, bias, N, E, P);

  attn_out<<<(N + 15) / 16, 1024, 0, stream>>>(cnt, csr_dst, Q16, KV16, bias,
                                               gate16, Wo, out, N);
}

// Round 7
// 238.653 us; speedup vs baseline: 1.0092x; 1.0092x over previous
//
#include <hip/hip_runtime.h>
#include <hip/hip_fp16.h>

#define DM 128
#define NHEADS 8
#define MAXDEG 64
#define SROW 136   // LDS row stride in halves: 128+8 pad (2-way bank alias = free)

typedef _Float16 half8 __attribute__((ext_vector_type(8)));
typedef _Float16 half2v __attribute__((ext_vector_type(2)));
typedef float floatx4 __attribute__((ext_vector_type(4)));

union H8 { half8 v; half2v h2[4]; _Float16 h[8]; };

// ================= fused: proj GEMM blocks [0,P) + CSR-build blocks [P,P+C) =================
// proj: X(Mx128,f32) @ Wcat^T(576x128) with inline f32->f16 W conversion during staging.
// one proj block = 128 M-rows x all 576 N-cols (9 chunks of 64). X read exactly once.
// chunk pairs: 0,1->Q  2,3->K(KV lo)  4,5->V(KV hi)  6,7->sigmoid gate  8->bias cols 512..519
// CSR blocks: 1 edge/thread (shortest dependent chain: load -> atomic -> scatter store).
__global__ __launch_bounds__(256) void proj_csr(
    const float* __restrict__ X, const float* __restrict__ Wqkv,
    const float* __restrict__ Wgate, const float* __restrict__ wbias,
    const float* __restrict__ b_gate,
    const int* __restrict__ nsrc, const int* __restrict__ ndst,
    int* __restrict__ cnt, int* __restrict__ csr_dst,
    _Float16* __restrict__ Q, _Float16* __restrict__ KV,
    _Float16* __restrict__ gate, float* __restrict__ bias,
    int M, int E, int P) {
  __shared__ _Float16 As[128 * SROW];
  __shared__ _Float16 Bs[64 * SROW];
  int tid = threadIdx.x;
  int bid = blockIdx.x;

  if (bid >= P) {
    // ---------------- CSR build role: 1 edge per thread ----------------
    int e = (bid - P) * 256 + tid;
    if (e < E) {
      int s = nsrc[e];
      int d = ndst[e];
      int p = atomicAdd(&cnt[s], 1);
      if (p < MAXDEG) csr_dst[(size_t)s * MAXDEG + p] = d;
    }
    return;
  }

  // ---------------- projection GEMM role ----------------
  int m0 = bid * 128;

  // stage A (fp32 -> fp16): 128 rows x 128 cols
#pragma unroll
  for (int i = 0; i < 4; i++) {
    int u = tid + i * 256;           // 0..1023
    int r = u >> 3;
    int cc = (u & 7) * 16;
    int gr = m0 + r;
    float4 f0, f1, f2, f3;
    if (gr < M) {
      const float4* src = (const float4*)(X + (size_t)gr * 128 + cc);
      f0 = src[0]; f1 = src[1]; f2 = src[2]; f3 = src[3];
    } else {
      f0 = f1 = f2 = f3 = make_float4(0.f, 0.f, 0.f, 0.f);
    }
    half8 h0 = {(_Float16)f0.x, (_Float16)f0.y, (_Float16)f0.z, (_Float16)f0.w,
                (_Float16)f1.x, (_Float16)f1.y, (_Float16)f1.z, (_Float16)f1.w};
    half8 h1 = {(_Float16)f2.x, (_Float16)f2.y, (_Float16)f2.z, (_Float16)f2.w,
                (_Float16)f3.x, (_Float16)f3.y, (_Float16)f3.z, (_Float16)f3.w};
    *(half8*)(As + r * SROW + cc) = h0;
    *(half8*)(As + r * SROW + cc + 8) = h1;
  }

  int wid = tid >> 6, lane = tid & 63;
  int quad = lane >> 4, l16 = lane & 15;
  int mw = wid * 32;                 // wave owns 32 M-rows

  for (int c = 0; c < 9; c++) {
    __syncthreads();                 // previous chunk's Bs readers done (orders A on c=0)
    // stage B chunk c with inline f32->f16 conversion
#pragma unroll
    for (int i = 0; i < 4; i++) {
      int u = tid + i * 256;         // 0..1023
      int r = u >> 4;                // 0..63
      int cc = (u & 15) * 8;
      int grow = c * 64 + r;
      const float* src = nullptr;
      if (grow < 384)      src = Wqkv + (size_t)grow * 128 + cc;
      else if (grow < 512) src = Wgate + (size_t)(grow - 384) * 128 + cc;
      else if (grow < 520) src = wbias + (size_t)(grow - 512) * 128 + cc;
      half8 h = {};
      if (src) {
        float4 f0 = ((const float4*)src)[0];
        float4 f1 = ((const float4*)src)[1];
        h = half8{(_Float16)f0.x, (_Float16)f0.y, (_Float16)f0.z, (_Float16)f0.w,
                  (_Float16)f1.x, (_Float16)f1.y, (_Float16)f1.z, (_Float16)f1.w};
      }
      *(half8*)(Bs + r * SROW + cc) = h;
    }
    __syncthreads();

    floatx4 acc[2][4] = {};
#pragma unroll
    for (int kc = 0; kc < 4; kc++) {
      int ko = kc * 32 + quad * 8;
      half8 a0 = *(const half8*)(As + (mw + l16) * SROW + ko);
      half8 a1 = *(const half8*)(As + (mw + 16 + l16) * SROW + ko);
      half8 b[4];
#pragma unroll
      for (int ni = 0; ni < 4; ni++)
        b[ni] = *(const half8*)(Bs + (ni * 16 + l16) * SROW + ko);
#pragma unroll
      for (int ni = 0; ni < 4; ni++) {
        acc[0][ni] = __builtin_amdgcn_mfma_f32_16x16x32_f16(a0, b[ni], acc[0][ni], 0, 0, 0);
        acc[1][ni] = __builtin_amdgcn_mfma_f32_16x16x32_f16(a1, b[ni], acc[1][ni], 0, 0, 0);
      }
    }

    if (c == 8) {                    // bias chunk: only cols 512..519 real
      if (l16 < 8) {
#pragma unroll
        for (int mi = 0; mi < 2; mi++)
#pragma unroll
          for (int r = 0; r < 4; r++) {
            int row = m0 + mw + mi * 16 + quad * 4 + r;
            if (row < M) bias[(size_t)row * 8 + l16] = acc[mi][0][r];
          }
      }
    } else {
      int reg = c >> 1;              // 0:Q 1:K 2:V 3:gate (wave-uniform)
#pragma unroll
      for (int mi = 0; mi < 2; mi++) {
#pragma unroll
        for (int ni = 0; ni < 4; ni++) {
          int colL = (c & 1) * 64 + ni * 16 + l16;   // 0..127 within region
#pragma unroll
          for (int r = 0; r < 4; r++) {
            int row = m0 + mw + mi * 16 + quad * 4 + r;
            if (row >= M) continue;
            float v = acc[mi][ni][r];
            if (reg == 0)      Q[(size_t)row * 128 + colL] = (_Float16)v;
            else if (reg == 1) KV[(size_t)row * 256 + colL] = (_Float16)v;
            else if (reg == 2) KV[(size_t)row * 256 + 128 + colL] = (_Float16)v;
            else gate[(size_t)row * 128 + colL] =
                   (_Float16)(1.0f / (1.0f + __expf(-(v + b_gate[colL]))));
          }
        }
      }
    }
  }
}

// ===== fused attention + output GEMM: 256 threads / 4 waves, 32 nodes per block =====
// Each wave processes 8 nodes SEQUENTIALLY (work per wave ~ Poisson(128): sigma/mu ~9%,
// so the single block barrier costs ~12%, not R6's ~60% one-node-per-wave tax).
// attn per node: quarter-wave per edge (R4's measured-60us shape + fdot2 dot).
// lane = qtr*16 + l16; lane owns channels [l16*8, l16*8+8); head = l16>>1.
// epilogue: gated 32x128 tile (LDS) @ Wo^T via MFMA, 2 chunks of 64 cols -> out f32.
__global__ __launch_bounds__(256) void attn_out(
    const int* __restrict__ cnt, const int* __restrict__ csr_dst,
    const _Float16* __restrict__ Q, const _Float16* __restrict__ KV,
    const float* __restrict__ bias, const _Float16* __restrict__ gate,
    const float* __restrict__ Wo, float* __restrict__ out, int N) {
  __shared__ _Float16 Ws[64 * SROW];    // Wo chunk (64 out-cols x 128 k), fp16
  __shared__ _Float16 Gs[32 * SROW];    // gated tile [node-slot][ch]
  int tid = threadIdx.x;
  int wid = tid >> 6, lane = tid & 63;
  int qtr = lane >> 4, l16 = lane & 15;
  int ch0 = l16 * 8;
  int n0 = blockIdx.x * 32;

  for (int i = 0; i < 8; i++) {
    int slot = wid * 8 + i;
    int n = n0 + slot;
    bool active = n < N;
    int n_eff = active ? n : 0;
    int deg = active ? cnt[n_eff] : 0;
    if (deg > MAXDEG) deg = MAXDEG;

    int dstv = csr_dst[(size_t)n_eff * MAXDEG + lane];   // coalesced

    H8 qu; qu.v = *(const half8*)(Q + (size_t)n_eff * DM + ch0);
    float bias_h = bias[(size_t)n_eff * NHEADS + (l16 >> 1)];

    float acc[8] = {};
    float den = 0.f;
    int iters = (deg + 3) >> 2;      // 4 edges per iteration (one per quarter-wave)

    H8 kc, vc; kc.v = half8{}; vc.v = half8{};
    bool bc = false;
    if (iters > 0) {
      bc = qtr < deg;
      int d = __shfl(dstv, qtr);
      d = bc ? d : 0;
      const _Float16* kvp = KV + (size_t)d * 256 + ch0;
      kc.v = *(const half8*)kvp;
      vc.v = *(const half8*)(kvp + 128);
    }
    for (int it = 0; it < iters; it++) {
      H8 kn, vn; kn.v = half8{}; vn.v = half8{};
      bool bn = false;
      if (it + 1 < iters) {          // wave-uniform branch
        int e = (it + 1) * 4 + qtr;  // <= 63 since deg <= 64
        bn = e < deg;
        int d = __shfl(dstv, e);
        d = bn ? d : 0;
        const _Float16* kvp = KV + (size_t)d * 256 + ch0;
        kn.v = *(const half8*)kvp;
        vn.v = *(const half8*)(kvp + 128);
      }
      // score: mixed-precision dot (v_dot2_f32_f16), then 16-channel head reduce
      float p = 0.f;
#pragma unroll
      for (int j = 0; j < 4; j++)
        p = __builtin_amdgcn_fdot2(qu.h2[j], kc.h2[j], p, false);
      p += __shfl_xor(p, 1);
      float w = __expf(p * 0.25f + bias_h);  // scale=1/sqrt(16); scores O(10), fp32-safe
      if (!bc) w = 0.f;
      den += w;
#pragma unroll
      for (int j = 0; j < 8; j++) acc[j] = fmaf(w, (float)vc.h[j], acc[j]);
      kc = kn; vc = vn; bc = bn;
    }
    // combine the four quarter-wave partials (butterfly)
#pragma unroll
    for (int j = 0; j < 8; j++) {
      acc[j] += __shfl_xor(acc[j], 16);
      acc[j] += __shfl_xor(acc[j], 32);
    }
    den += __shfl_xor(den, 16);
    den += __shfl_xor(den, 32);

    if (qtr == 0) {                  // lanes 0..15 hold the full 128-vector
      float inv = 1.0f / (den + 1e-12f);
      H8 gv; gv.v = *(const half8*)(gate + (size_t)n_eff * DM + ch0);
      half8 o;
#pragma unroll
      for (int j = 0; j < 8; j++)
        o[j] = active ? (_Float16)(acc[j] * inv * (float)gv.h[j]) : (_Float16)0.f;
      *(half8*)(Gs + slot * SROW + ch0) = o;
    }
  }

  __syncthreads();

  // output GEMM: out(32x128) = Gs(32x128) @ Wo^T, 2 chunks of 64 cols.
  // wave wid covers cols [chunk*64 + wid*16, +16); row-tiles mi=0,1 cover slots 0..31.
#pragma unroll
  for (int chunk = 0; chunk < 2; chunk++) {
    if (chunk) __syncthreads();      // protect Ws reuse
    // stage Wo rows [chunk*64, +64) fp32 -> fp16: 1024 half8-units, 4 per thread
#pragma unroll
    for (int i2 = 0; i2 < 4; i2++) {
      int u = tid + i2 * 256;
      int r = u >> 4;                // 0..63
      int cc = (u & 15) * 8;
      const float4* s = (const float4*)(Wo + (size_t)(chunk * 64 + r) * 128 + cc);
      float4 f0 = s[0], f1 = s[1];
      half8 h = {(_Float16)f0.x, (_Float16)f0.y, (_Float16)f0.z, (_Float16)f0.w,
                 (_Float16)f1.x, (_Float16)f1.y, (_Float16)f1.z, (_Float16)f1.w};
      *(half8*)(Ws + r * SROW + cc) = h;
    }
    __syncthreads();

    floatx4 oc[2] = {};
#pragma unroll
    for (int kc2 = 0; kc2 < 4; kc2++) {
      int ko = kc2 * 32 + qtr * 8;
      half8 b = *(const half8*)(Ws + (wid * 16 + l16) * SROW + ko);
#pragma unroll
      for (int mi = 0; mi < 2; mi++) {
        half8 a = *(const half8*)(Gs + (mi * 16 + l16) * SROW + ko);
        oc[mi] = __builtin_amdgcn_mfma_f32_16x16x32_f16(a, b, oc[mi], 0, 0, 0);
      }
    }
    int col = chunk * 64 + wid * 16 + l16;
#pragma unroll
    for (int mi = 0; mi < 2; mi++)
#pragma unroll
      for (int r = 0; r < 4; r++) {
        int row = n0 + mi * 16 + qtr * 4 + r;
        if (row < N) out[(size_t)row * 128 + col] = oc[mi][r];
      }
  }
}

extern "C" void kernel_launch(void* const* d_in, const int* in_sizes, int n_in,
                              void* d_out, int out_size, void* d_ws, size_t ws_size,
                              hipStream_t stream) {
  const float* X     = (const float*)d_in[0];
  const float* Wqkv  = (const float*)d_in[1];
  const float* wbias = (const float*)d_in[2];
  const float* Wgate = (const float*)d_in[3];
  const float* bgate = (const float*)d_in[4];
  const float* Wo    = (const float*)d_in[5];
  const int*   nsrc  = (const int*)d_in[6];
  const int*   ndst  = (const int*)d_in[7];
  int N = in_sizes[0] / 128;
  int E = in_sizes[6];
  float* out = (float*)d_out;

  char* p = (char*)d_ws;
  _Float16* Q16     = (_Float16*)p; p += (size_t)N * 128 * sizeof(_Float16);
  _Float16* KV16    = (_Float16*)p; p += (size_t)N * 256 * sizeof(_Float16);
  _Float16* gate16  = (_Float16*)p; p += (size_t)N * 128 * sizeof(_Float16);
  float* bias       = (float*)p;    p += (size_t)N * 8 * sizeof(float);
  int* cnt          = (int*)p;      p += (size_t)N * sizeof(int);
  int* csr_dst      = (int*)p;      p += (size_t)N * MAXDEG * sizeof(int);

  hipMemsetAsync(cnt, 0, (size_t)N * sizeof(int), stream);

  int P = (N + 127) / 128;                 // proj blocks
  int C = (E + 255) / 256;                 // csr blocks, 1 edge/thread
  proj_csr<<<P + C, 256, 0, stream>>>(X, Wqkv, Wgate, wbias, bgate, nsrc, ndst,
                                      cnt, csr_dst, Q16, KV16, gate16, bias, N, E, P);

  attn_out<<<(N + 31) / 32, 256, 0, stream>>>(cnt, csr_dst, Q16, KV16, bias,
                                              gate16, Wo, out, N);
}

// Round 8
// 236.968 us; speedup vs baseline: 1.0164x; 1.0071x over previous
//
#include <hip/hip_runtime.h>
#include <hip/hip_fp16.h>

#define DM 128
#define NHEADS 8
#define MAXDEG 64
#define SROW 136   // LDS row stride in halves: 128+8 pad (2-way bank alias = free)

typedef _Float16 half8 __attribute__((ext_vector_type(8)));
typedef _Float16 half2v __attribute__((ext_vector_type(2)));
typedef float floatx4 __attribute__((ext_vector_type(4)));

union H8 { half8 v; half2v h2[4]; _Float16 h[8]; };

__device__ inline half8 cvt8(const float4 f0, const float4 f1) {
  return half8{(_Float16)f0.x, (_Float16)f0.y, (_Float16)f0.z, (_Float16)f0.w,
               (_Float16)f1.x, (_Float16)f1.y, (_Float16)f1.z, (_Float16)f1.w};
}

// ================= fused: proj GEMM blocks [0,P) + CSR-build blocks [P,P+C) =================
// proj: X(Mx128,f32) @ Wcat^T(576x128). LDS = Bs ONLY (17.4 KB) so the co-resident CSR
// blocks keep high wave occupancy (R7's 52KB allocation capped everything at 25%).
// A-fragments load per-chunk from global X (fp32->fp16 inline); the 64KB X row-tile
// stays L2-resident across the 9 chunk re-reads.
// chunk pairs: 0,1->Q  2,3->K(KV lo)  4,5->V(KV hi)  6,7->sigmoid gate  8->bias cols 512..519
// CSR role: 4 edges/thread, independent atomic chains for memory-level parallelism.
__global__ __launch_bounds__(256) void proj_csr(
    const float* __restrict__ X, const float* __restrict__ Wqkv,
    const float* __restrict__ Wgate, const float* __restrict__ wbias,
    const float* __restrict__ b_gate,
    const int* __restrict__ nsrc, const int* __restrict__ ndst,
    int* __restrict__ cnt, int* __restrict__ csr_dst,
    _Float16* __restrict__ Q, _Float16* __restrict__ KV,
    _Float16* __restrict__ gate, float* __restrict__ bias,
    int M, int E, int P) {
  __shared__ _Float16 Bs[64 * SROW];
  int tid = threadIdx.x;
  int bid = blockIdx.x;

  if (bid >= P) {
    // ---------------- CSR build role: 4 edges per thread, independent chains ----------------
    int ebase = (bid - P) * 1024 + tid;
    int s[4], d[4];
#pragma unroll
    for (int j = 0; j < 4; j++) {
      int e = ebase + j * 256;
      bool v = e < E;
      s[j] = v ? nsrc[e] : -1;
      d[j] = v ? ndst[e] : 0;
    }
#pragma unroll
    for (int j = 0; j < 4; j++) {
      if (s[j] >= 0) {
        int p = atomicAdd(&cnt[s[j]], 1);
        if (p < MAXDEG) csr_dst[(size_t)s[j] * MAXDEG + p] = d[j];
      }
    }
    return;
  }

  // ---------------- projection GEMM role ----------------
  int m0 = bid * 128;
  int wid = tid >> 6, lane = tid & 63;
  int quad = lane >> 4, l16 = lane & 15;
  int mw = wid * 32;                 // wave owns 32 M-rows (2 tiles of 16)

  // clamped A row indices (pad rows compute garbage, stores are guarded)
  int ra0 = m0 + mw + l16;      if (ra0 > M - 1) ra0 = M - 1;
  int ra1 = m0 + mw + 16 + l16; if (ra1 > M - 1) ra1 = M - 1;
  const float* xp0 = X + (size_t)ra0 * 128 + quad * 8;
  const float* xp1 = X + (size_t)ra1 * 128 + quad * 8;

  for (int c = 0; c < 9; c++) {
    __syncthreads();                 // previous chunk's Bs readers done
    // stage B chunk c with inline f32->f16 conversion
#pragma unroll
    for (int i = 0; i < 4; i++) {
      int u = tid + i * 256;         // 0..1023
      int r = u >> 4;                // 0..63
      int cc = (u & 15) * 8;
      int grow = c * 64 + r;
      const float* src = nullptr;
      if (grow < 384)      src = Wqkv + (size_t)grow * 128 + cc;
      else if (grow < 512) src = Wgate + (size_t)(grow - 384) * 128 + cc;
      else if (grow < 520) src = wbias + (size_t)(grow - 512) * 128 + cc;
      half8 h = {};
      if (src) h = cvt8(((const float4*)src)[0], ((const float4*)src)[1]);
      *(half8*)(Bs + r * SROW + cc) = h;
    }
    __syncthreads();

    floatx4 acc[2][4] = {};
#pragma unroll
    for (int kc = 0; kc < 4; kc++) {
      int ko = kc * 32;              // + quad*8 folded into pointers
      half8 a0 = cvt8(((const float4*)(xp0 + ko))[0], ((const float4*)(xp0 + ko))[1]);
      half8 a1 = cvt8(((const float4*)(xp1 + ko))[0], ((const float4*)(xp1 + ko))[1]);
      half8 b[4];
#pragma unroll
      for (int ni = 0; ni < 4; ni++)
        b[ni] = *(const half8*)(Bs + (ni * 16 + l16) * SROW + ko + quad * 8);
#pragma unroll
      for (int ni = 0; ni < 4; ni++) {
        acc[0][ni] = __builtin_amdgcn_mfma_f32_16x16x32_f16(a0, b[ni], acc[0][ni], 0, 0, 0);
        acc[1][ni] = __builtin_amdgcn_mfma_f32_16x16x32_f16(a1, b[ni], acc[1][ni], 0, 0, 0);
      }
    }

    if (c == 8) {                    // bias chunk: only cols 512..519 real
      if (l16 < 8) {
#pragma unroll
        for (int mi = 0; mi < 2; mi++)
#pragma unroll
          for (int r = 0; r < 4; r++) {
            int row = m0 + mw + mi * 16 + quad * 4 + r;
            if (row < M) bias[(size_t)row * 8 + l16] = acc[mi][0][r];
          }
      }
    } else {
      int reg = c >> 1;              // 0:Q 1:K 2:V 3:gate (wave-uniform)
#pragma unroll
      for (int mi = 0; mi < 2; mi++) {
#pragma unroll
        for (int ni = 0; ni < 4; ni++) {
          int colL = (c & 1) * 64 + ni * 16 + l16;   // 0..127 within region
#pragma unroll
          for (int r = 0; r < 4; r++) {
            int row = m0 + mw + mi * 16 + quad * 4 + r;
            if (row >= M) continue;
            float v = acc[mi][ni][r];
            if (reg == 0)      Q[(size_t)row * 128 + colL] = (_Float16)v;
            else if (reg == 1) KV[(size_t)row * 256 + colL] = (_Float16)v;
            else if (reg == 2) KV[(size_t)row * 256 + 128 + colL] = (_Float16)v;
            else gate[(size_t)row * 128 + colL] =
                   (_Float16)(1.0f / (1.0f + __expf(-(v + b_gate[colL]))));
          }
        }
      }
    }
  }
}

// ===== fused attention + output GEMM: 256 threads / 4 waves, 32 nodes per block =====
// Each wave processes 8 nodes sequentially (sum of 8 Poisson(16) degrees: sigma/mu ~9%).
// attn per node: quarter-wave per edge; lane = qtr*16 + l16 owns channels [l16*8,+8).
// LDS = Gs ONLY (8.7 KB) -> wave-cap occupancy. Epilogue B-fragments (Wo rows) load
// straight from global (Wo is 64KB, L2/L3-hot) with inline f32->f16 convert.
__global__ __launch_bounds__(256) void attn_out(
    const int* __restrict__ cnt, const int* __restrict__ csr_dst,
    const _Float16* __restrict__ Q, const _Float16* __restrict__ KV,
    const float* __restrict__ bias, const _Float16* __restrict__ gate,
    const float* __restrict__ Wo, float* __restrict__ out, int N) {
  __shared__ _Float16 Gs[32 * SROW];    // gated tile [node-slot][ch]
  int tid = threadIdx.x;
  int wid = tid >> 6, lane = tid & 63;
  int qtr = lane >> 4, l16 = lane & 15;
  int ch0 = l16 * 8;
  int n0 = blockIdx.x * 32;

  for (int i = 0; i < 8; i++) {
    int slot = wid * 8 + i;
    int n = n0 + slot;
    bool active = n < N;
    int n_eff = active ? n : 0;
    int deg = active ? cnt[n_eff] : 0;
    if (deg > MAXDEG) deg = MAXDEG;

    int dstv = csr_dst[(size_t)n_eff * MAXDEG + lane];   // coalesced

    H8 qu; qu.v = *(const half8*)(Q + (size_t)n_eff * DM + ch0);
    float bias_h = bias[(size_t)n_eff * NHEADS + (l16 >> 1)];

    float acc[8] = {};
    float den = 0.f;
    int iters = (deg + 3) >> 2;      // 4 edges per iteration (one per quarter-wave)

    H8 kc, vc; kc.v = half8{}; vc.v = half8{};
    bool bc = false;
    if (iters > 0) {
      bc = qtr < deg;
      int d = __shfl(dstv, qtr);
      d = bc ? d : 0;
      const _Float16* kvp = KV + (size_t)d * 256 + ch0;
      kc.v = *(const half8*)kvp;
      vc.v = *(const half8*)(kvp + 128);
    }
    for (int it = 0; it < iters; it++) {
      H8 kn, vn; kn.v = half8{}; vn.v = half8{};
      bool bn = false;
      if (it + 1 < iters) {          // wave-uniform branch
        int e = (it + 1) * 4 + qtr;  // <= 63 since deg <= 64
        bn = e < deg;
        int d = __shfl(dstv, e);
        d = bn ? d : 0;
        const _Float16* kvp = KV + (size_t)d * 256 + ch0;
        kn.v = *(const half8*)kvp;
        vn.v = *(const half8*)(kvp + 128);
      }
      // score: mixed-precision dot (v_dot2_f32_f16), then 16-channel head reduce
      float p = 0.f;
#pragma unroll
      for (int j = 0; j < 4; j++)
        p = __builtin_amdgcn_fdot2(qu.h2[j], kc.h2[j], p, false);
      p += __shfl_xor(p, 1);
      float w = __expf(p * 0.25f + bias_h);  // scale=1/sqrt(16); scores O(10), fp32-safe
      if (!bc) w = 0.f;
      den += w;
#pragma unroll
      for (int j = 0; j < 8; j++) acc[j] = fmaf(w, (float)vc.h[j], acc[j]);
      kc = kn; vc = vn; bc = bn;
    }
    // combine the four quarter-wave partials (butterfly)
#pragma unroll
    for (int j = 0; j < 8; j++) {
      acc[j] += __shfl_xor(acc[j], 16);
      acc[j] += __shfl_xor(acc[j], 32);
    }
    den += __shfl_xor(den, 16);
    den += __shfl_xor(den, 32);

    if (qtr == 0) {                  // lanes 0..15 hold the full 128-vector
      float inv = 1.0f / (den + 1e-12f);
      H8 gv; gv.v = *(const half8*)(gate + (size_t)n_eff * DM + ch0);
      half8 o;
#pragma unroll
      for (int j = 0; j < 8; j++)
        o[j] = active ? (_Float16)(acc[j] * inv * (float)gv.h[j]) : (_Float16)0.f;
      *(half8*)(Gs + slot * SROW + ch0) = o;
    }
  }

  __syncthreads();

  // output GEMM: out(32x128) = Gs(32x128) @ Wo^T, 2 chunks of 64 cols.
  // wave wid covers cols [chunk*64 + wid*16, +16); B-frag rows = Wo out-cols, from global.
#pragma unroll
  for (int chunk = 0; chunk < 2; chunk++) {
    int col = chunk * 64 + wid * 16 + l16;          // this lane's out col / Wo row
    const float* wp = Wo + (size_t)col * 128 + qtr * 8;
    floatx4 oc[2] = {};
#pragma unroll
    for (int kc2 = 0; kc2 < 4; kc2++) {
      int ko = kc2 * 32;
      half8 b = cvt8(((const float4*)(wp + ko))[0], ((const float4*)(wp + ko))[1]);
#pragma unroll
      for (int mi = 0; mi < 2; mi++) {
        half8 a = *(const half8*)(Gs + (mi * 16 + l16) * SROW + ko + qtr * 8);
        oc[mi] = __builtin_amdgcn_mfma_f32_16x16x32_f16(a, b, oc[mi], 0, 0, 0);
      }
    }
#pragma unroll
    for (int mi = 0; mi < 2; mi++)
#pragma unroll
      for (int r = 0; r < 4; r++) {
        int row = n0 + mi * 16 + qtr * 4 + r;
        if (row < N) out[(size_t)row * 128 + col] = oc[mi][r];
      }
  }
}

extern "C" void kernel_launch(void* const* d_in, const int* in_sizes, int n_in,
                              void* d_out, int out_size, void* d_ws, size_t ws_size,
                              hipStream_t stream) {
  const float* X     = (const float*)d_in[0];
  const float* Wqkv  = (const float*)d_in[1];
  const float* wbias = (const float*)d_in[2];
  const float* Wgate = (const float*)d_in[3];
  const float* bgate = (const float*)d_in[4];
  const float* Wo    = (const float*)d_in[5];
  const int*   nsrc  = (const int*)d_in[6];
  const int*   ndst  = (const int*)d_in[7];
  int N = in_sizes[0] / 128;
  int E = in_sizes[6];
  float* out = (float*)d_out;

  char* p = (char*)d_ws;
  _Float16* Q16     = (_Float16*)p; p += (size_t)N * 128 * sizeof(_Float16);
  _Float16* KV16    = (_Float16*)p; p += (size_t)N * 256 * sizeof(_Float16);
  _Float16* gate16  = (_Float16*)p; p += (size_t)N * 128 * sizeof(_Float16);
  float* bias       = (float*)p;    p += (size_t)N * 8 * sizeof(float);
  int* cnt          = (int*)p;      p += (size_t)N * sizeof(int);
  int* csr_dst      = (int*)p;      p += (size_t)N * MAXDEG * sizeof(int);

  hipMemsetAsync(cnt, 0, (size_t)N * sizeof(int), stream);

  int P = (N + 127) / 128;                 // proj blocks
  int C = (E + 1023) / 1024;               // csr blocks, 4 edges/thread
  proj_csr<<<P + C, 256, 0, stream>>>(X, Wqkv, Wgate, wbias, bgate, nsrc, ndst,
                                      cnt, csr_dst, Q16, KV16, gate16, bias, N, E, P);

  attn_out<<<(N + 31) / 32, 256, 0, stream>>>(cnt, csr_dst, Q16, KV16, bias,
                                              gate16, Wo, out, N);
}

// Round 9
// 229.148 us; speedup vs baseline: 1.0511x; 1.0341x over previous
//
#include <hip/hip_runtime.h>
#include <hip/hip_fp16.h>

#define DM 128
#define NHEADS 8
#define MAXDEG 64
#define CNTSTRIDE 16   // one counter per 64B line: avoids cross-XCD same-line atomic ping-pong
#define SROW 136       // LDS row stride in halves: 128+8 pad (2-way bank alias = free)

typedef _Float16 half8 __attribute__((ext_vector_type(8)));
typedef float floatx4 __attribute__((ext_vector_type(4)));

union H8 { half8 v; _Float16 h[8]; };

__device__ inline half8 cvt8(const float4 f0, const float4 f1) {
  return half8{(_Float16)f0.x, (_Float16)f0.y, (_Float16)f0.z, (_Float16)f0.w,
               (_Float16)f1.x, (_Float16)f1.y, (_Float16)f1.z, (_Float16)f1.w};
}

// ================= fused: proj GEMM blocks [0,P) + CSR-build blocks [P,P+C) =================
// (R5 structure — measured 76 us.) proj: X(Mx128,f32) @ Wcat^T(576x128), inline f32->f16 W
// staging, one block = 128 M-rows x all 576 N-cols (9 chunks of 64). X read exactly once.
// chunk pairs: 0,1->Q  2,3->K(KV lo)  4,5->V(KV hi)  6,7->sigmoid gate  8->bias cols 512..519
// CSR blocks: 8192 edges each, 32 edges/thread batched 8-deep.
__global__ __launch_bounds__(256) void proj_csr(
    const float* __restrict__ X, const float* __restrict__ Wqkv,
    const float* __restrict__ Wgate, const float* __restrict__ wbias,
    const float* __restrict__ b_gate,
    const int* __restrict__ nsrc, const int* __restrict__ ndst,
    int* __restrict__ cnt, int* __restrict__ csr_dst,
    _Float16* __restrict__ Q, _Float16* __restrict__ KV,
    _Float16* __restrict__ gate, float* __restrict__ bias,
    int M, int E, int P) {
  __shared__ _Float16 As[128 * SROW];
  __shared__ _Float16 Bs[64 * SROW];
  int tid = threadIdx.x;
  int bid = blockIdx.x;

  if (bid >= P) {
    // ---------------- CSR build role ----------------
    int ebase = (bid - P) * 8192;
    for (int g = 0; g < 4; g++) {
      int s[8], d[8];
#pragma unroll
      for (int j = 0; j < 8; j++) {
        int e = ebase + (g * 8 + j) * 256 + tid;
        s[j] = (e < E) ? nsrc[e] : -1;
        d[j] = (e < E) ? ndst[e] : 0;
      }
#pragma unroll
      for (int j = 0; j < 8; j++) {
        if (s[j] >= 0) {
          int p = atomicAdd(&cnt[(size_t)s[j] * CNTSTRIDE], 1);
          if (p < MAXDEG) csr_dst[(size_t)s[j] * MAXDEG + p] = d[j];
        }
      }
    }
    return;
  }

  // ---------------- projection GEMM role ----------------
  int m0 = bid * 128;

  // stage A (fp32 -> fp16): 128 rows x 128 cols
#pragma unroll
  for (int i = 0; i < 4; i++) {
    int u = tid + i * 256;           // 0..1023
    int r = u >> 3;
    int cc = (u & 7) * 16;
    int gr = m0 + r;
    float4 f0, f1, f2, f3;
    if (gr < M) {
      const float4* src = (const float4*)(X + (size_t)gr * 128 + cc);
      f0 = src[0]; f1 = src[1]; f2 = src[2]; f3 = src[3];
    } else {
      f0 = f1 = f2 = f3 = make_float4(0.f, 0.f, 0.f, 0.f);
    }
    *(half8*)(As + r * SROW + cc) = cvt8(f0, f1);
    *(half8*)(As + r * SROW + cc + 8) = cvt8(f2, f3);
  }

  int wid = tid >> 6, lane = tid & 63;
  int quad = lane >> 4, l16 = lane & 15;
  int mw = wid * 32;                 // wave owns 32 M-rows

  for (int c = 0; c < 9; c++) {
    __syncthreads();                 // previous chunk's Bs readers done (orders A on c=0)
    // stage B chunk c with inline f32->f16 conversion
#pragma unroll
    for (int i = 0; i < 4; i++) {
      int u = tid + i * 256;         // 0..1023
      int r = u >> 4;                // 0..63
      int cc = (u & 15) * 8;
      int grow = c * 64 + r;
      const float* src = nullptr;
      if (grow < 384)      src = Wqkv + (size_t)grow * 128 + cc;
      else if (grow < 512) src = Wgate + (size_t)(grow - 384) * 128 + cc;
      else if (grow < 520) src = wbias + (size_t)(grow - 512) * 128 + cc;
      half8 h = {};
      if (src) h = cvt8(((const float4*)src)[0], ((const float4*)src)[1]);
      *(half8*)(Bs + r * SROW + cc) = h;
    }
    __syncthreads();

    floatx4 acc[2][4] = {};
#pragma unroll
    for (int kc = 0; kc < 4; kc++) {
      int ko = kc * 32 + quad * 8;
      half8 a0 = *(const half8*)(As + (mw + l16) * SROW + ko);
      half8 a1 = *(const half8*)(As + (mw + 16 + l16) * SROW + ko);
      half8 b[4];
#pragma unroll
      for (int ni = 0; ni < 4; ni++)
        b[ni] = *(const half8*)(Bs + (ni * 16 + l16) * SROW + ko);
#pragma unroll
      for (int ni = 0; ni < 4; ni++) {
        acc[0][ni] = __builtin_amdgcn_mfma_f32_16x16x32_f16(a0, b[ni], acc[0][ni], 0, 0, 0);
        acc[1][ni] = __builtin_amdgcn_mfma_f32_16x16x32_f16(a1, b[ni], acc[1][ni], 0, 0, 0);
      }
    }

    if (c == 8) {                    // bias chunk: only cols 512..519 real
      if (l16 < 8) {
#pragma unroll
        for (int mi = 0; mi < 2; mi++)
#pragma unroll
          for (int r = 0; r < 4; r++) {
            int row = m0 + mw + mi * 16 + quad * 4 + r;
            if (row < M) bias[(size_t)row * 8 + l16] = acc[mi][0][r];
          }
      }
    } else {
      int reg = c >> 1;              // 0:Q 1:K 2:V 3:gate (wave-uniform)
#pragma unroll
      for (int mi = 0; mi < 2; mi++) {
#pragma unroll
        for (int ni = 0; ni < 4; ni++) {
          int colL = (c & 1) * 64 + ni * 16 + l16;   // 0..127 within region
#pragma unroll
          for (int r = 0; r < 4; r++) {
            int row = m0 + mw + mi * 16 + quad * 4 + r;
            if (row >= M) continue;
            float v = acc[mi][ni][r];
            if (reg == 0)      Q[(size_t)row * 128 + colL] = (_Float16)v;
            else if (reg == 1) KV[(size_t)row * 256 + colL] = (_Float16)v;
            else if (reg == 2) KV[(size_t)row * 256 + 128 + colL] = (_Float16)v;
            else gate[(size_t)row * 128 + colL] =
                   (_Float16)(1.0f / (1.0f + __expf(-(v + b_gate[colL]))));
          }
        }
      }
    }
  }
}

// ============ fused attention (R4 structure — measured 60 us — + KV interleave) ============
// one wave per node; quarter-wave per edge; lane = qtr*16 + l16 owns channels [l16*8,+8);
// head = l16>>1. Prefetch depth 1, plain fp32 dot + 1 shfl head-reduce.
__global__ __launch_bounds__(256) void attn_fused(
    const int* __restrict__ cnt, const int* __restrict__ csr_dst,
    const _Float16* __restrict__ Q, const _Float16* __restrict__ KV,
    const float* __restrict__ bias, const _Float16* __restrict__ gate,
    _Float16* __restrict__ gated, int N) {
  int wave = threadIdx.x >> 6, lane = threadIdx.x & 63;
  int n = blockIdx.x * 4 + wave;
  if (n >= N) return;
  int deg = cnt[(size_t)n * CNTSTRIDE];
  if (deg > MAXDEG) deg = MAXDEG;
  int qtr = lane >> 4, l16 = lane & 15;
  int ch0 = l16 * 8;

  int dstv = csr_dst[(size_t)n * MAXDEG + lane];   // coalesced; garbage beyond deg (guarded)

  H8 qu; qu.v = *(const half8*)(Q + (size_t)n * DM + ch0);
  float qf[8];
#pragma unroll
  for (int j = 0; j < 8; j++) qf[j] = (float)qu.h[j];
  float bias_h = bias[(size_t)n * NHEADS + (l16 >> 1)];

  float acc[8] = {};
  float den = 0.f;
  int iters = (deg + 3) >> 2;        // 4 edges per iteration (one per quarter-wave)

  H8 kc, vc; kc.v = half8{}; vc.v = half8{};
  bool bc = false;
  if (iters > 0) {
    bc = qtr < deg;
    int d = __shfl(dstv, qtr);
    d = bc ? d : 0;
    const _Float16* kvp = KV + (size_t)d * 256 + ch0;
    kc.v = *(const half8*)kvp;
    vc.v = *(const half8*)(kvp + 128);
  }
  for (int it = 0; it < iters; it++) {
    H8 kn, vn; kn.v = half8{}; vn.v = half8{};
    bool bn = false;
    if (it + 1 < iters) {            // wave-uniform branch
      int e = (it + 1) * 4 + qtr;    // <= 63 since deg <= 64
      bn = e < deg;
      int d = __shfl(dstv, e);
      d = bn ? d : 0;
      const _Float16* kvp = KV + (size_t)d * 256 + ch0;
      kn.v = *(const half8*)kvp;
      vn.v = *(const half8*)(kvp + 128);
    }
    float p = 0.f;
#pragma unroll
    for (int j = 0; j < 8; j++) p += qf[j] * (float)kc.h[j];
    p += __shfl_xor(p, 1);           // 16-channel head dot
    float w = __expf(p * 0.25f + bias_h);   // scale=1/sqrt(16); scores O(10), fp32-safe
    if (!bc) w = 0.f;
    den += w;
#pragma unroll
    for (int j = 0; j < 8; j++) acc[j] = fmaf(w, (float)vc.h[j], acc[j]);
    kc = kn; vc = vn; bc = bn;
  }
  // combine the four quarter-wave partials (butterfly)
#pragma unroll
  for (int j = 0; j < 8; j++) {
    acc[j] += __shfl_xor(acc[j], 16);
    acc[j] += __shfl_xor(acc[j], 32);
  }
  den += __shfl_xor(den, 16);
  den += __shfl_xor(den, 32);

  if (qtr == 0) {                    // lanes 0..15 hold the full 128-vector
    float inv = 1.0f / (den + 1e-12f);
    H8 gv; gv.v = *(const half8*)(gate + (size_t)n * DM + ch0);
    half8 o;
#pragma unroll
    for (int j = 0; j < 8; j++) o[j] = (_Float16)(acc[j] * inv * (float)gv.h[j]);
    *(half8*)(gated + (size_t)n * DM + ch0) = o;
  }
}

// ================= final GEMM: gated16(Mx128) @ Wo^T(128x128,f32->f16 inline) -> out(f32) =====
__global__ __launch_bounds__(256) void final_gemm_mfma(
    const _Float16* __restrict__ A, const float* __restrict__ Wo,
    float* __restrict__ C, int M) {
  __shared__ _Float16 As[128 * SROW];
  __shared__ _Float16 Bs[64 * SROW];
  int tid = threadIdx.x;
  int m0 = blockIdx.x * 128, n0 = blockIdx.y * 64;
#pragma unroll
  for (int i = 0; i < 8; i++) {
    int u = tid + i * 256;
    int r = u >> 4;
    int cc = (u & 15) * 8;
    int gr = m0 + r;
    int4 val = make_int4(0, 0, 0, 0);
    if (gr < M) val = *(const int4*)(A + (size_t)gr * 128 + cc);
    *(int4*)(As + r * SROW + cc) = val;
  }
#pragma unroll
  for (int i = 0; i < 4; i++) {
    int u = tid + i * 256;
    int r = u >> 4;
    int cc = (u & 15) * 8;
    const float* src = Wo + (size_t)(n0 + r) * 128 + cc;
    *(half8*)(Bs + r * SROW + cc) = cvt8(((const float4*)src)[0], ((const float4*)src)[1]);
  }
  __syncthreads();

  int wid = tid >> 6, lane = tid & 63;
  int quad = lane >> 4, l16 = lane & 15;
  int mw = (wid >> 1) * 64;
  int nw = (wid & 1) * 32;

  floatx4 acc[4][2] = {};
#pragma unroll
  for (int kc = 0; kc < 4; kc++) {
    int ko = kc * 32 + quad * 8;
    half8 a[4], b[2];
#pragma unroll
    for (int mi = 0; mi < 4; mi++)
      a[mi] = *(const half8*)(As + (mw + mi * 16 + l16) * SROW + ko);
#pragma unroll
    for (int ni = 0; ni < 2; ni++)
      b[ni] = *(const half8*)(Bs + (nw + ni * 16 + l16) * SROW + ko);
#pragma unroll
    for (int mi = 0; mi < 4; mi++)
#pragma unroll
      for (int ni = 0; ni < 2; ni++)
        acc[mi][ni] = __builtin_amdgcn_mfma_f32_16x16x32_f16(a[mi], b[ni], acc[mi][ni], 0, 0, 0);
  }
#pragma unroll
  for (int mi = 0; mi < 4; mi++) {
#pragma unroll
    for (int ni = 0; ni < 2; ni++) {
      int col = n0 + nw + ni * 16 + l16;
#pragma unroll
      for (int r = 0; r < 4; r++) {
        int row = m0 + mw + mi * 16 + quad * 4 + r;
        if (row >= M) continue;
        C[(size_t)row * 128 + col] = acc[mi][ni][r];
      }
    }
  }
}

extern "C" void kernel_launch(void* const* d_in, const int* in_sizes, int n_in,
                              void* d_out, int out_size, void* d_ws, size_t ws_size,
                              hipStream_t stream) {
  const float* X     = (const float*)d_in[0];
  const float* Wqkv  = (const float*)d_in[1];
  const float* wbias = (const float*)d_in[2];
  const float* Wgate = (const float*)d_in[3];
  const float* bgate = (const float*)d_in[4];
  const float* Wo    = (const float*)d_in[5];
  const int*   nsrc  = (const int*)d_in[6];
  const int*   ndst  = (const int*)d_in[7];
  int N = in_sizes[0] / 128;
  int E = in_sizes[6];
  float* out = (float*)d_out;

  char* p = (char*)d_ws;
  _Float16* Q16     = (_Float16*)p; p += (size_t)N * 128 * sizeof(_Float16);
  _Float16* KV16    = (_Float16*)p; p += (size_t)N * 256 * sizeof(_Float16);
  _Float16* gate16  = (_Float16*)p; p += (size_t)N * 128 * sizeof(_Float16);
  _Float16* gated16 = (_Float16*)p; p += (size_t)N * 128 * sizeof(_Float16);
  float* bias       = (float*)p;    p += (size_t)N * 8 * sizeof(float);
  int* cnt          = (int*)p;      p += (size_t)N * CNTSTRIDE * sizeof(int);
  int* csr_dst      = (int*)p;      p += (size_t)N * MAXDEG * sizeof(int);

  hipMemsetAsync(cnt, 0, (size_t)N * CNTSTRIDE * sizeof(int), stream);

  int P = (N + 127) / 128;                 // proj blocks
  int C = (E + 8191) / 8192;               // csr blocks (32 edges/thread, batch-8)
  proj_csr<<<P + C, 256, 0, stream>>>(X, Wqkv, Wgate, wbias, bgate, nsrc, ndst,
                                      cnt, csr_dst, Q16, KV16, gate16, bias, N, E, P);

  attn_fused<<<(N + 3) / 4, 256, 0, stream>>>(cnt, csr_dst, Q16, KV16, bias,
                                              gate16, gated16, N);

  dim3 fg((N + 127) / 128, 2);
  final_gemm_mfma<<<fg, 256, 0, stream>>>(gated16, Wo, out, N);
}